// Round 5
// baseline (624.256 us; speedup 1.0000x reference)
//
#include <hip/hip_runtime.h>
#include <hip/hip_bf16.h>

#define T_LEN 512
#define BATCH 8
#define HID 128
#define NSTEP 576   // 512 + 64 anti-diagonal steps for the skewed wave DP

// ---------------------------------------------------------------------------
// Weight repack: [Cout][Cin][3] -> [Cout][Cin][4] (k=3 zero). Enables aligned
// s_load_dwordx4 weight fetch in the conv kernel.
// ---------------------------------------------------------------------------
__global__ void repack_w_kernel(const float* __restrict__ in,
                                float* __restrict__ out, int n)  // n = Cout*Cin
{
    int i = blockIdx.x * blockDim.x + threadIdx.x;
    if (i < n) {
        float a = in[i * 3 + 0], b = in[i * 3 + 1], c = in[i * 3 + 2];
        *reinterpret_cast<float4*>(out + i * 4) = make_float4(a, b, c, 0.0f);
    }
}

// ---------------------------------------------------------------------------
// Conv block: y[b,co,t] = lrelu(bias[co] + sum_{ci,k} w[co,ci,k]*x_pad[b,ci,t+k-1])
// reflect pad 1. 512 threads = 8 waves; each wave owns a uniform co-pair so
// padded weights stream via s_load_dwordx4. fma order identical to the
// verified kernel. Grid (T/64, Cout/16, B).
// ---------------------------------------------------------------------------
__global__ __launch_bounds__(512) void conv_block_kernel(
    const float* __restrict__ x, const float* __restrict__ wp,
    const float* __restrict__ bias, float* __restrict__ y,
    int Cin, int Cout)
{
    __shared__ float xs[128 * 66];
    const int b   = blockIdx.z;
    const int t0  = blockIdx.x * 64;
    const int tid = threadIdx.x;
    const int tl  = tid & 63;

    const float* xb = x + (size_t)b * Cin * T_LEN;
    for (int idx = tid; idx < Cin * 66; idx += 512) {
        int ci = idx / 66;
        int tt = idx - ci * 66;
        int g  = t0 + tt - 1;
        g = (g < 0) ? 1 : (g >= T_LEN ? T_LEN - 2 : g);
        xs[idx] = xb[ci * T_LEN + g];
    }
    __syncthreads();

    const int wave = __builtin_amdgcn_readfirstlane(tid >> 6);
    const int co0  = blockIdx.y * 16 + 2 * wave;   // Cout even (80/126/128)
    if (co0 < Cout) {
        const float* __restrict__ wq0 = wp + (size_t)co0 * Cin * 4;
        const float* __restrict__ wq1 = wq0 + Cin * 4;
        float acc0 = 0.0f, acc1 = 0.0f;
#pragma unroll 4
        for (int ci = 0; ci < Cin; ++ci) {
            float xm = xs[ci * 66 + tl];
            float x0 = xs[ci * 66 + tl + 1];
            float xp = xs[ci * 66 + tl + 2];
            const float4 w0 = *reinterpret_cast<const float4*>(wq0 + ci * 4);
            const float4 w1 = *reinterpret_cast<const float4*>(wq1 + ci * 4);
            acc0 = fmaf(w0.x, xm, acc0);
            acc0 = fmaf(w0.y, x0, acc0);
            acc0 = fmaf(w0.z, xp, acc0);
            acc1 = fmaf(w1.x, xm, acc1);
            acc1 = fmaf(w1.y, x0, acc1);
            acc1 = fmaf(w1.z, xp, acc1);
        }
        float v0 = acc0 + bias[co0];
        float v1 = acc1 + bias[co0 + 1];
        v0 = (v0 >= 0.0f) ? v0 : 0.2f * v0;
        v1 = (v1 >= 0.0f) ? v1 : 0.2f * v1;
        y[((size_t)b * Cout + co0) * T_LEN + t0 + tl]     = v0;
        y[((size_t)b * Cout + co0 + 1) * T_LEN + t0 + tl] = v1;
    }
}

// ---------------------------------------------------------------------------
// dist[b,m,n] = sqrt( sum_h (k[b,h,m]-q[b,h,n])^2 ) raw; fold global min/max
// into mm (nonneg float -> uint bit-order). Unchanged from passing rounds.
// ---------------------------------------------------------------------------
__global__ __launch_bounds__(256) void dist_kernel(
    const float* __restrict__ q, const float* __restrict__ k,
    float* __restrict__ dist, unsigned* __restrict__ mm)
{
    __shared__ __align__(16) float ks[HID * 32];
    __shared__ __align__(16) float qs[HID * 32];
    __shared__ float red[8];

    const int b  = blockIdx.z;
    const int m0 = blockIdx.y * 32;
    const int n0 = blockIdx.x * 32;
    const int tid = threadIdx.x;

    const float* qb = q + (size_t)b * HID * T_LEN;
    const float* kb = k + (size_t)b * HID * T_LEN;

    for (int idx = tid; idx < HID * 32; idx += 256) {
        int h = idx >> 5, c = idx & 31;
        ks[idx] = kb[h * T_LEN + m0 + c];
        qs[idx] = qb[h * T_LEN + n0 + c];
    }
    __syncthreads();

    const int nn = tid & 31;
    const int mq = (tid >> 5) * 4;

    float a0 = 0.f, a1 = 0.f, a2 = 0.f, a3 = 0.f;
    for (int h = 0; h < HID; ++h) {
        float qv = qs[h * 32 + nn];
        const float4 kv = *reinterpret_cast<const float4*>(&ks[h * 32 + mq]);
        float d0 = kv.x - qv, d1 = kv.y - qv, d2 = kv.z - qv, d3 = kv.w - qv;
        a0 = fmaf(d0, d0, a0);
        a1 = fmaf(d1, d1, a1);
        a2 = fmaf(d2, d2, a2);
        a3 = fmaf(d3, d3, a3);
    }
    float v0 = sqrtf(a0), v1 = sqrtf(a1), v2 = sqrtf(a2), v3 = sqrtf(a3);

    float* drow = dist + ((size_t)b * T_LEN + m0 + mq) * T_LEN + n0 + nn;
    drow[0 * T_LEN] = v0;
    drow[1 * T_LEN] = v1;
    drow[2 * T_LEN] = v2;
    drow[3 * T_LEN] = v3;

    float mnv = fminf(fminf(v0, v1), fminf(v2, v3));
    float mxv = fmaxf(fmaxf(v0, v1), fmaxf(v2, v3));
#pragma unroll
    for (int off = 32; off >= 1; off >>= 1) {
        mnv = fminf(mnv, __shfl_xor(mnv, off, 64));
        mxv = fmaxf(mxv, __shfl_xor(mxv, off, 64));
    }
    int wid = tid >> 6;
    if ((tid & 63) == 0) { red[wid * 2] = mnv; red[wid * 2 + 1] = mxv; }
    __syncthreads();
    if (tid == 0) {
        float mn = fminf(fminf(red[0], red[2]), fminf(red[4], red[6]));
        float mx = fmaxf(fmaxf(red[1], red[3]), fmaxf(red[5], red[7]));
        atomicMin(&mm[0], __float_as_uint(mn));
        atomicMax(&mm[1], __float_as_uint(mx));
    }
}

// ---------------------------------------------------------------------------
// Fused normalize + shear: v = (raw-mn)/rng written in-place to dist (output)
// AND into diagonal-major dsk[b][t][m] = v(m, n=t-(m>>3)), so the DTW wave
// kernel's per-step read is one contiguous 2KB wave load. 64x64 tiles, LDS
// staged. Same IEEE division both places -> bit-identical values.
// ---------------------------------------------------------------------------
__global__ __launch_bounds__(512) void norm_shear_kernel(
    float* __restrict__ dist, float* __restrict__ dsk,
    const unsigned* __restrict__ mm)
{
    __shared__ float tile[64][65];
    const float mn  = __uint_as_float(mm[0]);
    const float rng = __uint_as_float(mm[1]) - mn;
    const int b  = blockIdx.z;
    const int m0 = blockIdx.y * 64;
    const int n0 = blockIdx.x * 64;
    const int tid  = threadIdx.x;
    const int lane = tid & 63;
    const int wv   = tid >> 6;       // 0..7

    float* D = dist + (size_t)b * T_LEN * T_LEN;
#pragma unroll
    for (int r = 0; r < 8; ++r) {
        int lm = wv + r * 8;             // local row
        float v = (D[(m0 + lm) * T_LEN + n0 + lane] - mn) / rng;
        D[(m0 + lm) * T_LEN + n0 + lane] = v;
        tile[lm][lane] = v;
    }
    __syncthreads();

    float* dskb = dsk + (size_t)b * NSTEP * T_LEN;
    const int tbase = n0 + (m0 >> 3);
#pragma unroll
    for (int it = 0; it < 9; ++it) {
        int t_local = wv + it * 8;       // 0..71, valid up to 70
        int ln = t_local - (lane >> 3);
        if (t_local <= 70 && ln >= 0 && ln < 64)
            dskb[(size_t)(tbase + t_local) * T_LEN + m0 + lane] = tile[lane][ln];
    }
}

// ---------------------------------------------------------------------------
// DTW: single-wave register-resident skewed DP, diagonal-major input, depth-8
// software prefetch (fully coalesced 2KB wave loads). One 64-thread block per
// batch. Lane p owns rows 8p..8p+7; at step t computes column j = t-p.
// Cross-lane boundary costs via __shfl_up. Per-cell float op sequence
// identical to the verified kernels. Choices 2-bit packed in LDS, tiled
// [r>>2][j>>4][r&3] so backtrack fetches a 4x16 tile per b128 read.
// ---------------------------------------------------------------------------
#define DTW_STEP(T, DA, DB) do {                                              \
    int j = (T) - p;                                                          \
    float u_top = __shfl_up(L[7], 1, 64);                                     \
    float d_top = __shfl_up(prevL7, 1, 64);                                   \
    prevL7 = L[7];                                                            \
    if ((unsigned)j < 512u) {                                                 \
        float dvs[8] = {DA.x, DA.y, DA.z, DA.w, DB.x, DB.y, DB.z, DB.w};      \
        int sh = (j & 15) * 2;                                                \
        float cur, oldL, prevrow;                                             \
        unsigned ch;                                                          \
        if (p == 0) {                                                         \
            cur = (j == 0) ? dvs[0] : (L[0] + dvs[0]); ch = 1u;               \
        } else if (j == 0) {                                                  \
            cur = u_top + dvs[0]; ch = 2u;                                    \
        } else {                                                              \
            float pd = d_top, lf = L[0], pu = u_top;                          \
            float m = fminf(fminf(pd, lf), pu);                               \
            ch = (pd == m) ? 0u : ((lf == m) ? 1u : 2u);                      \
            cur = m + dvs[0];                                                 \
        }                                                                     \
        oldL = L[0]; L[0] = cur; prevrow = cur; pk[0] |= ch << sh;            \
        _Pragma("unroll")                                                     \
        for (int u = 1; u < 8; ++u) {                                         \
            if (j == 0) { cur = prevrow + dvs[u]; ch = 2u; }                  \
            else {                                                            \
                float pd = oldL, lf = L[u], pu = prevrow;                     \
                float m = fminf(fminf(pd, lf), pu);                           \
                ch = (pd == m) ? 0u : ((lf == m) ? 1u : 2u);                  \
                cur = m + dvs[u];                                             \
            }                                                                 \
            oldL = L[u]; L[u] = cur; prevrow = cur; pk[u] |= ch << sh;        \
        }                                                                     \
        if ((j & 15) == 15) {                                                 \
            int w4 = (j >> 4) * 4;                                            \
            *reinterpret_cast<uint4*>(&cho[p * 256 + w4]) =                   \
                make_uint4(pk[0], pk[1], pk[2], pk[3]);                       \
            *reinterpret_cast<uint4*>(&cho[p * 256 + 128 + w4]) =             \
                make_uint4(pk[4], pk[5], pk[6], pk[7]);                       \
            pk[0] = pk[1] = pk[2] = pk[3] = 0u;                               \
            pk[4] = pk[5] = pk[6] = pk[7] = 0u;                               \
        }                                                                     \
    }                                                                         \
} while (0)

__device__ __forceinline__ float4 ld4d(const float* dskb, int t, int off) {
    return *reinterpret_cast<const float4*>(dskb + (size_t)t * T_LEN + off);
}

__global__ __launch_bounds__(64) void dtw_wave_kernel(
    const float* __restrict__ dsk, const int* __restrict__ rlen,
    float* __restrict__ path)
{
    __shared__ unsigned cho[512 * 32];   // 64 KiB

    const int b  = blockIdx.x;
    const int p  = threadIdx.x;          // lane, owns rows 8p..8p+7
    const int r0 = p * 8;
    const float* dskb = dsk + (size_t)b * NSTEP * T_LEN;

    float L[8];
    float prevL7 = 1e30f;
#pragma unroll
    for (int u = 0; u < 8; ++u) L[u] = 1e30f;
    unsigned pk[8] = {0u, 0u, 0u, 0u, 0u, 0u, 0u, 0u};

    float4 P0[8], P1[8];
#pragma unroll
    for (int u = 0; u < 8; ++u) {
        P0[u] = ld4d(dskb, u, r0);
        P1[u] = ld4d(dskb, u, r0 + 4);
    }

    for (int t0 = 0; t0 < NSTEP; t0 += 8) {
#pragma unroll
        for (int u = 0; u < 8; ++u) {
            int t  = t0 + u;
            int tn = t + 8; tn = (tn < NSTEP) ? tn : (NSTEP - 1);
            float4 Na = ld4d(dskb, tn, r0);
            float4 Nb = ld4d(dskb, tn, r0 + 4);
            DTW_STEP(t, P0[u], P1[u]);
            P0[u] = Na; P1[u] = Nb;
        }
    }

    __syncthreads();

    if (p == 0) {
        int Lr = rlen[b];
        int ix = Lr - 1, iy = Lr - 1;
        float* po = path + (size_t)b * T_LEN * T_LEN;
        po[ix * T_LEN + iy] = 1.0f;
        while (ix > 0 || iy > 0) {
            uint4 tw = *reinterpret_cast<const uint4*>(
                &cho[((ix >> 2) * 32 + (iy >> 4)) * 4]);
            int tr = ix >> 2, tc = iy >> 4;
            while (true) {
                int sel = ix & 3;
                unsigned wvv = (sel & 2) ? ((sel & 1) ? tw.w : tw.z)
                                         : ((sel & 1) ? tw.y : tw.x);
                int c = (wvv >> ((iy & 15) * 2)) & 3;
                ix -= (c != 1);
                iy -= (c != 2);
                po[ix * T_LEN + iy] = 1.0f;
                if (!(ix > 0 || iy > 0)) break;
                if ((ix >> 2) != tr || (iy >> 4) != tc) break;
            }
        }
    }
}

// ---------------------------------------------------------------------------
extern "C" void kernel_launch(void* const* d_in, const int* in_sizes, int n_in,
                              void* d_out, int out_size, void* d_ws, size_t ws_size,
                              hipStream_t stream)
{
    (void)in_sizes; (void)n_in; (void)out_size; (void)ws_size;

    const float* vec   = (const float*)d_in[0];
    const float* music = (const float*)d_in[1];
    const int*   rlen  = (const int*)  d_in[2];
    const float* qw1 = (const float*)d_in[3];  const float* qb1 = (const float*)d_in[4];
    const float* qw2 = (const float*)d_in[5];  const float* qb2 = (const float*)d_in[6];
    const float* qw3 = (const float*)d_in[7];  const float* qb3 = (const float*)d_in[8];
    const float* kw1 = (const float*)d_in[9];  const float* kb1 = (const float*)d_in[10];
    const float* kw2 = (const float*)d_in[11]; const float* kb2 = (const float*)d_in[12];
    const float* kw3 = (const float*)d_in[13]; const float* kb3 = (const float*)d_in[14];

    float* out = (float*)d_out;
    const size_t mat_elems = (size_t)BATCH * T_LEN * T_LEN;
    float* path_out = out;
    float* dist_out = out + mat_elems;

    // ws layout (lifetime-overlapped):
    //   dsk   [0, 9437184)            written by norm_shear (convs+weights dead)
    //   conv  [0, 8MB)  qA/qB/kA/kB   alive repack..dist   (overlaps dsk: ok)
    //   wrep  [8MB, 9691200)          alive repack..convs  (overlaps dsk tail: ok)
    //   mm    [9691200, 9691208)      alive dist..norm — OUTSIDE everything.
    //   (round-4 bug: mm sat at 9437184, inside kw3p -> repack clobbered it)
    char* ws = (char*)d_ws;
    const size_t bufB = (size_t)BATCH * HID * T_LEN * sizeof(float);  // 2 MiB
    float* dsk = (float*)ws;
    float* qA = (float*)(ws + 0 * bufB);
    float* qB = (float*)(ws + 1 * bufB);
    float* kA = (float*)(ws + 2 * bufB);
    float* kB = (float*)(ws + 3 * bufB);
    char* wr = ws + 4 * bufB;   // 8 MiB
    float* qw1p = (float*)(wr);                       // 126*126*16 = 254016 B
    float* qw2p = (float*)(wr + 254016);              // 128*126*16 = 258048 B
    float* qw3p = (float*)(wr + 512064);              // 128*128*16 = 262144 B
    float* kw1p = (float*)(wr + 774208);              // 80*80*16   = 102400 B
    float* kw2p = (float*)(wr + 876608);              // 128*80*16  = 163840 B
    float* kw3p = (float*)(wr + 1040448);             // 128*128*16 = 262144 B -> ends 1302592
    unsigned* mm = (unsigned*)(ws + 9691200);         // past wrep end (8MB+1302592)

    hipMemsetAsync(path_out, 0, mat_elems * sizeof(float), stream);
    hipMemsetAsync(mm, 0xFF, 4, stream);
    hipMemsetAsync(mm + 1, 0x00, 4, stream);

    repack_w_kernel<<<(126 * 126 + 255) / 256, 256, 0, stream>>>(qw1, qw1p, 126 * 126);
    repack_w_kernel<<<(128 * 126 + 255) / 256, 256, 0, stream>>>(qw2, qw2p, 128 * 126);
    repack_w_kernel<<<(128 * 128 + 255) / 256, 256, 0, stream>>>(qw3, qw3p, 128 * 128);
    repack_w_kernel<<<(80 * 80 + 255) / 256, 256, 0, stream>>>(kw1, kw1p, 80 * 80);
    repack_w_kernel<<<(128 * 80 + 255) / 256, 256, 0, stream>>>(kw2, kw2p, 128 * 80);
    repack_w_kernel<<<(128 * 128 + 255) / 256, 256, 0, stream>>>(kw3, kw3p, 128 * 128);

    dim3 cb(512);
    conv_block_kernel<<<dim3(8, 8, 8), cb, 0, stream>>>(vec, qw1p, qb1, qA, 126, 126);
    conv_block_kernel<<<dim3(8, 8, 8), cb, 0, stream>>>(qA,  qw2p, qb2, qB, 126, 128);
    conv_block_kernel<<<dim3(8, 8, 8), cb, 0, stream>>>(qB,  qw3p, qb3, qA, 128, 128);
    conv_block_kernel<<<dim3(8, 5, 8), cb, 0, stream>>>(music, kw1p, kb1, kA, 80, 80);
    conv_block_kernel<<<dim3(8, 8, 8), cb, 0, stream>>>(kA,   kw2p, kb2, kB, 80, 128);
    conv_block_kernel<<<dim3(8, 8, 8), cb, 0, stream>>>(kB,   kw3p, kb3, kA, 128, 128);

    dist_kernel<<<dim3(16, 16, 8), dim3(256), 0, stream>>>(qA, kA, dist_out, mm);

    norm_shear_kernel<<<dim3(8, 8, 8), dim3(512), 0, stream>>>(dist_out, dsk, mm);

    dtw_wave_kernel<<<dim3(BATCH), dim3(64), 0, stream>>>(dsk, rlen, path_out);
}